// Round 14
// baseline (597.688 us; speedup 1.0000x reference)
//
#include <hip/hip_runtime.h>

// ---------------------------------------------------------------------------
// out = x @ W_base^T + x[t] @ (DeltaW[j] + A[j]B[j]);  T=8192, D=4096, J=8, R=16.
// W_tot[j][o][i] = Wb[o][i] + DW[j][i][o] + (A@B)[i][o]  (bf16, [N][K]), then
// ONE grouped GEMM (merged pass1 + split-K tail, R13-proven, 383us).
// R14: convert(x->bf16) + zero-tail FUSED into the build dispatch (both are
//      independent BW-bound streams; serial split wasted ~35us of HBM idle).
//      Grid = 4096 build + 2048 convert + 512 zero blocks, branch per block.
// ---------------------------------------------------------------------------

#define T_TOKENS 8192
#define DIM 4096
#define NADAPT 8
#define RANK 16

#define BM2 256
#define GRIDX1 512            // pass-1 domain: mt<32, 32x16, %8==0
#define GRIDXALL 1024         // + 512 tail split-K blocks

#define BUILD_BLK 4096
#define CONV_BLK 2048
#define ZERO_BLK 512
#define FUSED_GRID (BUILD_BLK + CONV_BLK + ZERO_BLK)

#define BM1 128
#define MAXT1 72

typedef __attribute__((ext_vector_type(8))) short bf16x8;
typedef __attribute__((ext_vector_type(4))) float f32x4;

__device__ __forceinline__ unsigned short f2bf(float f) {
  union { float f; unsigned u; } v; v.f = f;
  unsigned r = v.u + 0x7FFFu + ((v.u >> 16) & 1u);   // RNE
  return (unsigned short)(r >> 16);
}

__device__ __forceinline__ void gload_lds16(const void* g, void* l) {
  __builtin_amdgcn_global_load_lds(
      (const __attribute__((address_space(1))) void*)g,
      (__attribute__((address_space(3))) void*)l, 16, 0, 0);
}

template <int N> __device__ __forceinline__ void vmwait() {
  if constexpr (N == 0)      asm volatile("s_waitcnt vmcnt(0)" ::: "memory");
  else if constexpr (N == 4) asm volatile("s_waitcnt vmcnt(4)" ::: "memory");
  else if constexpr (N == 8) asm volatile("s_waitcnt vmcnt(8)" ::: "memory");
  // N < 0: no wait
}

// ---------------------------------------------------------------------------
// Kernel 1: group tokens by adapter (stable compaction), tile descriptors.
// ---------------------------------------------------------------------------
__global__ void prep_kernel(const int* __restrict__ idx, int* __restrict__ perm,
                            int* __restrict__ meta, int padm) {
  __shared__ int s_cnt[NADAPT];
  __shared__ int s_padoff[NADAPT + 1];
  __shared__ int s_wsum[16];
  const int tid = threadIdx.x;
  const int lane = tid & 63;
  const int wave = tid >> 6;

  if (tid < NADAPT) s_cnt[tid] = 0;
  __syncthreads();
  for (int t = tid; t < T_TOKENS; t += 1024) atomicAdd(&s_cnt[idx[t]], 1);
  __syncthreads();

  if (tid == 0) {
    int off = 0, nt = 0;
    for (int j = 0; j < NADAPT; ++j) {
      meta[j] = s_cnt[j];
      s_padoff[j] = off;
      const int c = s_cnt[j];
      const int ntj = (c + padm - 1) / padm;
      for (int i = 0; i < ntj; ++i) {
        meta[32 + 3 * nt + 0] = j;
        meta[32 + 3 * nt + 1] = off + i * padm;
        meta[32 + 3 * nt + 2] = min(padm, c - i * padm);
        ++nt;
      }
      off += ntj * padm;
    }
    s_padoff[NADAPT] = off;
    meta[17] = nt;
    for (int j = 0; j <= NADAPT; ++j) meta[8 + j] = s_padoff[j];
  }
  __syncthreads();

  const int total_pad = s_padoff[NADAPT];
  for (int t = tid; t < total_pad; t += 1024) perm[t] = -1;
  __syncthreads();

  for (int j = 0; j < NADAPT; ++j) {
    int base = s_padoff[j];
    for (int c0 = 0; c0 < T_TOKENS; c0 += 1024) {
      const int t = c0 + tid;
      const int flag = (idx[t] == j) ? 1 : 0;
      const unsigned long long bal = __ballot(flag);
      const int wpos = __popcll(bal & ((1ULL << lane) - 1ULL));
      if (lane == 0) s_wsum[wave] = __popcll(bal);
      __syncthreads();
      int woff = 0, ctot = 0;
      for (int w = 0; w < 16; ++w) {
        const int v = s_wsum[w];
        if (w < wave) woff += v;
        ctot += v;
      }
      if (flag) perm[base + woff + wpos] = t;
      base += ctot;
      __syncthreads();
    }
  }
}

// ---------------------------------------------------------------------------
// Kernel 2 (fallback tiers only): x fp32 -> bf16 + zero tail out-rows.
// ---------------------------------------------------------------------------
__global__ void convert_zero_kernel(const float* __restrict__ x,
                                    unsigned short* __restrict__ xb,
                                    const int* __restrict__ perm,
                                    const int* __restrict__ meta,
                                    float* __restrict__ out, int do_zero) {
  const int tid = threadIdx.x;
  if (blockIdx.x < 16384) {
    const long long i = (long long)blockIdx.x * 256 + tid;
    const f32x4* x4 = (const f32x4*)x;
    const f32x4 a = __builtin_nontemporal_load(&x4[2 * i]);
    const f32x4 b = __builtin_nontemporal_load(&x4[2 * i + 1]);
    uint4 o;
    o.x = (unsigned)f2bf(a.x) | ((unsigned)f2bf(a.y) << 16);
    o.y = (unsigned)f2bf(a.z) | ((unsigned)f2bf(a.w) << 16);
    o.z = (unsigned)f2bf(b.x) | ((unsigned)f2bf(b.y) << 16);
    o.w = (unsigned)f2bf(b.z) | ((unsigned)f2bf(b.w) << 16);
    ((uint4*)xb)[i] = o;
  } else if (do_zero) {
    const int b = blockIdx.x - 16384;
    const int mth = b >> 5;
    const int strip = b & 31;
    const int ntiles = meta[17];
    const int mt = 32 + (mth >> 1);
    if (mt >= ntiles) return;
    const int pbase = meta[32 + 3 * mt + 1] + (mth & 1) * 128;
    const int row = tid >> 1;
    const int c0 = strip * 128 + (tid & 1) * 64;
    const int pr = perm[pbase + row];
    if (pr < 0) return;
    float4* p = (float4*)(out + (size_t)pr * DIM + c0);
    const float4 z = {0.f, 0.f, 0.f, 0.f};
#pragma unroll
    for (int k = 0; k < 16; ++k) p[k] = z;
  }
}

// ---------------------------------------------------------------------------
// Kernel 3a (npp==8): FUSED dispatch — blocks [0,4096): j-looped W_tot build
// (R9-proven, NT loads); [4096,6144): x->bf16 convert (8 chunks/block);
// [6144,6656): zero tail out-rows. Convert/zero fill build's BW-latency gaps.
// ---------------------------------------------------------------------------
__global__ __launch_bounds__(256) void fused_build_kernel(
    const float* __restrict__ Wb, const float* __restrict__ Am,
    const float* __restrict__ Bm, const float* __restrict__ DW,
    unsigned short* __restrict__ Wt,
    const float* __restrict__ x, unsigned short* __restrict__ xb,
    const int* __restrict__ perm, const int* __restrict__ meta,
    float* __restrict__ out) {
  const int tid = threadIdx.x;
  const int blk = blockIdx.x;

  if (blk >= BUILD_BLK) {
    if (blk < BUILD_BLK + CONV_BLK) {
      // ---- convert: 8 chunks of 256 uint4-pairs per block ----
      const int cb = blk - BUILD_BLK;
      const f32x4* x4 = (const f32x4*)x;
#pragma unroll
      for (int k = 0; k < 8; ++k) {
        const long long i = ((long long)cb * 8 + k) * 256 + tid;
        const f32x4 a = __builtin_nontemporal_load(&x4[2 * i]);
        const f32x4 b = __builtin_nontemporal_load(&x4[2 * i + 1]);
        uint4 o;
        o.x = (unsigned)f2bf(a.x) | ((unsigned)f2bf(a.y) << 16);
        o.y = (unsigned)f2bf(a.z) | ((unsigned)f2bf(a.w) << 16);
        o.z = (unsigned)f2bf(b.x) | ((unsigned)f2bf(b.y) << 16);
        o.w = (unsigned)f2bf(b.z) | ((unsigned)f2bf(b.w) << 16);
        ((uint4*)xb)[i] = o;
      }
    } else {
      // ---- zero tail out-rows (split-K atomic targets) ----
      const int b = blk - BUILD_BLK - CONV_BLK;   // 0..511
      const int mth = b >> 5;
      const int strip = b & 31;
      const int ntiles = meta[17];
      const int mt = 32 + (mth >> 1);
      if (mt >= ntiles) return;
      const int pbase = meta[32 + 3 * mt + 1] + (mth & 1) * 128;
      const int row = tid >> 1;
      const int c0 = strip * 128 + (tid & 1) * 64;
      const int pr = perm[pbase + row];
      if (pr < 0) return;
      float4* p = (float4*)(out + (size_t)pr * DIM + c0);
      const float4 z = {0.f, 0.f, 0.f, 0.f};
#pragma unroll
      for (int k = 0; k < 16; ++k) p[k] = z;
    }
    return;
  }

  // ---- build: W_tot tile (i0,o0) for all 8 adapters (R9-proven) ----
  const int i0 = (blk & 63) << 6;
  const int o0 = (blk >> 6) << 6;
  __shared__ float Dl[2][64 * 64];
  __shared__ float Alt[2][16][68];
  __shared__ float Bl[2][16][68];
  const int to = (tid >> 4) << 2;
  const int ti = (tid & 15) << 2;

  f32x4 wbr[4];
#pragma unroll
  for (int m = 0; m < 4; ++m)
    wbr[m] = __builtin_nontemporal_load(
        (const f32x4*)(Wb + (size_t)(o0 + to + m) * DIM + i0 + ti));

  const int di = tid >> 4;
  const int do4 = (tid & 15) << 2;
  const int ar_i = tid >> 2, ar_r4 = (tid & 3) << 2;
  const int br_r = tid >> 4, br_o4 = (tid & 15) << 2;

  f32x4 dwr[4];
  float4 ar, brv;
  {
    const float* dwp = DW + (size_t)i0 * DIM + o0;
#pragma unroll
    for (int q = 0; q < 4; ++q)
      dwr[q] = __builtin_nontemporal_load(
          (const f32x4*)(dwp + (size_t)(q * 16 + di) * DIM + do4));
    ar = *(const float4*)(Am + ((size_t)(i0 + ar_i)) * RANK + ar_r4);
    brv = *(const float4*)(Bm + (size_t)br_r * DIM + o0 + br_o4);
  }
#pragma unroll
  for (int q = 0; q < 4; ++q) {
    const int i = q * 16 + di;
    const int iq = i >> 2, ie = i & 3;
#pragma unroll
    for (int k = 0; k < 4; ++k) {
      const int o = do4 + k;
      Dl[0][o * 64 + (((iq ^ (o & 15)) << 2) | ie)] = dwr[q][k];
    }
  }
#pragma unroll
  for (int k = 0; k < 4; ++k) Alt[0][ar_r4 + k][ar_i] = ((const float*)&ar)[k];
  *(float4*)&Bl[0][br_r][br_o4] = brv;
  __syncthreads();

  for (int j = 0; j < NADAPT; ++j) {
    const int pb = j & 1;
    if (j + 1 < NADAPT) {
      const float* dwp = DW + ((size_t)(j + 1) * DIM + i0) * DIM + o0;
#pragma unroll
      for (int q = 0; q < 4; ++q)
        dwr[q] = __builtin_nontemporal_load(
            (const f32x4*)(dwp + (size_t)(q * 16 + di) * DIM + do4));
      ar = *(const float4*)(Am + ((size_t)(j + 1) * DIM + i0 + ar_i) * RANK + ar_r4);
      brv = *(const float4*)(Bm + ((size_t)(j + 1) * RANK + br_r) * DIM + o0 + br_o4);
    }
    float acc[4][4];
#pragma unroll
    for (int m = 0; m < 4; ++m) {
      const int o = to + m;
      const float4 d = *(const float4*)&Dl[pb][o * 64 + (((ti >> 2) ^ (o & 15)) << 2)];
      acc[m][0] = wbr[m].x + d.x; acc[m][1] = wbr[m].y + d.y;
      acc[m][2] = wbr[m].z + d.z; acc[m][3] = wbr[m].w + d.w;
    }
#pragma unroll
    for (int r = 0; r < RANK; ++r) {
      const float4 av = *(const float4*)&Alt[pb][r][ti];
      const float4 bv = *(const float4*)&Bl[pb][r][to];
#pragma unroll
      for (int m = 0; m < 4; ++m) {
        const float b = ((const float*)&bv)[m];
        acc[m][0] += b * av.x; acc[m][1] += b * av.y;
        acc[m][2] += b * av.z; acc[m][3] += b * av.w;
      }
    }
#pragma unroll
    for (int m = 0; m < 4; ++m) {
      const int o = to + m;
      const unsigned lo = (unsigned)f2bf(acc[m][0]) | ((unsigned)f2bf(acc[m][1]) << 16);
      const unsigned hi = (unsigned)f2bf(acc[m][2]) | ((unsigned)f2bf(acc[m][3]) << 16);
      uint2 pk; pk.x = lo; pk.y = hi;
      *(uint2*)(Wt + ((size_t)j * DIM + o0 + o) * DIM + i0 + ti) = pk;
    }
    if (j + 1 < NADAPT) {
      const int nb = pb ^ 1;
#pragma unroll
      for (int q = 0; q < 4; ++q) {
        const int i = q * 16 + di;
        const int iq = i >> 2, ie = i & 3;
#pragma unroll
        for (int k = 0; k < 4; ++k) {
          const int o = do4 + k;
          Dl[nb][o * 64 + (((iq ^ (o & 15)) << 2) | ie)] = dwr[q][k];
        }
      }
#pragma unroll
      for (int k = 0; k < 4; ++k) Alt[nb][ar_r4 + k][ar_i] = ((const float*)&ar)[k];
      *(float4*)&Bl[nb][br_r][br_o4] = brv;
      __syncthreads();
    }
  }
}

// ---------------------------------------------------------------------------
// Kernel 3b (npp<8 fallback tiers): per-adapter W_tot build (R4-proven).
// ---------------------------------------------------------------------------
__global__ __launch_bounds__(256) void build_wtot_kernel(
    const float* __restrict__ Wb, const float* __restrict__ Am,
    const float* __restrict__ Bm, const float* __restrict__ DW,
    unsigned short* __restrict__ Wt, int j0) {
  const int jj = blockIdx.z;
  const int j = j0 + jj;
  const int i0 = blockIdx.x << 6;
  const int o0 = blockIdx.y << 6;
  __shared__ float Dl[64 * 64];
  __shared__ float Alt[16][68];
  __shared__ float Bl[16][68];
  const int tid = threadIdx.x;

  const float* dwp = DW + ((size_t)j * DIM + i0) * DIM + o0;
#pragma unroll
  for (int q = 0; q < 4; ++q) {
    const int lin = q * 256 + tid;
    const int i = lin >> 4;
    const int o4 = (lin & 15) << 2;
    const float4 v = *(const float4*)(dwp + (size_t)i * DIM + o4);
    const int iq = i >> 2, ie = i & 3;
#pragma unroll
    for (int k = 0; k < 4; ++k) {
      const int o = o4 + k;
      Dl[o * 64 + (((iq ^ (o & 15)) << 2) | ie)] = ((const float*)&v)[k];
    }
  }
  {
    const int ai = tid >> 2, r4 = (tid & 3) << 2;
    const float4 v = *(const float4*)(Am + ((size_t)j * DIM + i0 + ai) * RANK + r4);
#pragma unroll
    for (int k = 0; k < 4; ++k) Alt[r4 + k][ai] = ((const float*)&v)[k];
  }
  {
    const int br = tid >> 4, bo4 = (tid & 15) << 2;
    const float4 v = *(const float4*)(Bm + ((size_t)j * RANK + br) * DIM + o0 + bo4);
    *(float4*)&Bl[br][bo4] = v;
  }
  __syncthreads();

  const int to = (tid >> 4) << 2;
  const int ti = (tid & 15) << 2;
  float acc[4][4];

#pragma unroll
  for (int m = 0; m < 4; ++m) {
    const int o = to + m;
    const float4 w = *(const float4*)(Wb + (size_t)(o0 + o) * DIM + i0 + ti);
    const float4 d = *(const float4*)&Dl[o * 64 + (((ti >> 2) ^ (o & 15)) << 2)];
    acc[m][0] = w.x + d.x; acc[m][1] = w.y + d.y;
    acc[m][2] = w.z + d.z; acc[m][3] = w.w + d.w;
  }
#pragma unroll
  for (int r = 0; r < RANK; ++r) {
    const float4 av = *(const float4*)&Alt[r][ti];
    const float4 bv = *(const float4*)&Bl[r][to];
#pragma unroll
    for (int m = 0; m < 4; ++m) {
      const float b = ((const float*)&bv)[m];
      acc[m][0] += b * av.x; acc[m][1] += b * av.y;
      acc[m][2] += b * av.z; acc[m][3] += b * av.w;
    }
  }
#pragma unroll
  for (int m = 0; m < 4; ++m) {
    const int o = to + m;
    const unsigned lo = (unsigned)f2bf(acc[m][0]) | ((unsigned)f2bf(acc[m][1]) << 16);
    const unsigned hi = (unsigned)f2bf(acc[m][2]) | ((unsigned)f2bf(acc[m][3]) << 16);
    uint2 pk; pk.x = lo; pk.y = hi;
    *(uint2*)(Wt + ((size_t)jj * DIM + o0 + o) * DIM + i0 + ti) = pk;
  }
}

// ---------------------------------------------------------------------------
// Kernel 4a: merged 8-phase 256x256 grouped GEMM (R13-proven).
// blocks <512: mt<32, full K (ntk=64), NT-store epilogue, XCD-swizzled.
// blocks >=512: tail mt>=32, split-K x4 (ntk=16, kc=0..3), atomicAdd epilogue.
// ---------------------------------------------------------------------------
template <int BUF, int KK, int MQ, int VME, int SGRP, int SOP, int SKH, bool DOST>
__device__ __forceinline__ void do_phase(
    char* smem, int tid, int stile,
    const unsigned short* const* aB, const unsigned short* const* bB,
    const int* aoff, const int* boff, bf16x8* bfr, f32x4 (*acc)[4]) {
  const int grp = (BUF * 2 + KK) * 16384;
  if constexpr (MQ == 0) {
#pragma unroll
    for (int n = 0; n < 4; ++n)
      bfr[n] = *(const bf16x8*)(smem + 65536 + grp + boff[n]);
  }
  bf16x8 afr[4];
#pragma unroll
  for (int i = 0; i < 4; ++i)
    afr[i] = *(const bf16x8*)(smem + grp + aoff[MQ * 4 + i]);
  if constexpr (DOST) {
    const unsigned short* const* bs = SOP ? bB : aB;
#pragma unroll
    for (int q = 0; q < 2; ++q)
      gload_lds16(bs[q] + stile * 64 + SKH * 32,
                  smem + SOP * 65536 + SGRP * 16384 + q * 8192 + tid * 16);
  }
  __builtin_amdgcn_s_barrier();
  asm volatile("s_waitcnt lgkmcnt(0)" ::: "memory");
  __builtin_amdgcn_s_setprio(1);
#pragma unroll
  for (int i = 0; i < 4; ++i)
#pragma unroll
    for (int n = 0; n < 4; ++n)
      acc[MQ * 4 + i][n] =
          __builtin_amdgcn_mfma_f32_16x16x32_bf16(afr[i], bfr[n], acc[MQ * 4 + i][n], 0, 0, 0);
  __builtin_amdgcn_s_setprio(0);
  vmwait<VME>();
  __builtin_amdgcn_s_barrier();
}

template <int SGRP, int SOP, int SKH>
__device__ __forceinline__ void do_stage(
    char* smem, int tid, int stile,
    const unsigned short* const* aB, const unsigned short* const* bB) {
  const unsigned short* const* bs = SOP ? bB : aB;
#pragma unroll
  for (int q = 0; q < 2; ++q)
    gload_lds16(bs[q] + stile * 64 + SKH * 32,
                smem + SOP * 65536 + SGRP * 16384 + q * 8192 + tid * 16);
}

__global__ __launch_bounds__(512, 2) void gemm8_all_kernel(
    const unsigned short* __restrict__ xb, const unsigned short* __restrict__ Wt,
    const int* __restrict__ perm, const int* __restrict__ meta,
    float* __restrict__ out) {
  extern __shared__ char smem[];
  const int ntiles = meta[17];
  const int flat = blockIdx.x;
  int mt, nt, kc, ntk;
  bool tailk;
  if (flat < GRIDX1) {
    const int swz = (flat & 7) * (GRIDX1 / 8) + (flat >> 3);   // XCD-chunked
    mt = swz >> 4; nt = swz & 15; kc = 0; ntk = 64; tailk = false;
  } else {
    const int f = flat - GRIDX1;
    kc = f >> 7;                    // 0..3 K-chunks
    const int r = f & 127;
    mt = 32 + (r >> 4); nt = r & 15; ntk = 16; tailk = true;
  }
  if (mt >= ntiles) return;
  const int adapter = meta[32 + 3 * mt];
  const int pbase = meta[32 + 3 * mt + 1];
  const int nbase = nt << 8;
  const size_t kbase = (size_t)kc * ((size_t)ntk * 64);

  const int tid = threadIdx.x;
  const int lane = tid & 63;
  const int wave = tid >> 6;
  const int wr = wave >> 2, wc = wave & 3;       // 2M x 4N waves
  const int fr = lane & 15, kg = lane >> 4;

  int aoff[8], boff[4];
#pragma unroll
  for (int m = 0; m < 8; ++m) {
    const int row = wr * 128 + m * 16 + fr;
    const int r = row >> 1, hf = row & 1;
    const int c = ((hf << 2) | kg) ^ (r & 7);
    aoff[m] = r * 128 + c * 16;
  }
#pragma unroll
  for (int n = 0; n < 4; ++n) {
    const int row = wc * 64 + n * 16 + fr;
    const int r = row >> 1, hf = row & 1;
    const int c = ((hf << 2) | kg) ^ (r & 7);
    boff[n] = r * 128 + c * 16;
  }

  // stage source pointers (pre-swizzled global, linear LDS dest — rule 21)
  const unsigned short* aB[2];
  const unsigned short* bB[2];
#pragma unroll
  for (int q = 0; q < 2; ++q) {
    const int L = q * 512 + tid;
    const int r = L >> 3, c = L & 7;
    const int s = c ^ (r & 7);
    const int grow = 2 * r + (s >> 2);
    const int gk = (s & 3) << 3;
    int pr = perm[pbase + grow];
    if (pr < 0) pr = 0;
    aB[q] = xb + (size_t)pr * DIM + gk + kbase;
    bB[q] = Wt + ((size_t)adapter * DIM + nbase + grow) * DIM + gk + kbase;
  }

  const f32x4 zero = {0.f, 0.f, 0.f, 0.f};
  f32x4 acc[8][4];
#pragma unroll
  for (int m = 0; m < 8; ++m)
#pragma unroll
    for (int n = 0; n < 4; ++n) acc[m][n] = zero;
  bf16x8 bfr[4];

  // prologue: tile0 (buf0) both k-halves, tile1 (buf1) k-half0
  do_stage<0, 0, 0>(smem, tid, 0, aB, bB);
  do_stage<0, 1, 0>(smem, tid, 0, aB, bB);
  do_stage<1, 0, 1>(smem, tid, 0, aB, bB);
  do_stage<1, 1, 1>(smem, tid, 0, aB, bB);
  do_stage<2, 0, 0>(smem, tid, 1, aB, bB);
  do_stage<2, 1, 0>(smem, tid, 1, aB, bB);
  vmwait<8>();
  __builtin_amdgcn_s_barrier();

  // main loop: iter computes tiles 2it (buf0), 2it+1 (buf1)
  for (int it = 0; it < ntk / 2 - 1; ++it) {
    const int t1 = 2 * it + 1, t2 = 2 * it + 2, t3 = 2 * it + 3;
    do_phase<0, 0, 0, -1, 3, 0, 1, true>(smem, tid, t1, aB, bB, aoff, boff, bfr, acc);
    do_phase<0, 0, 1,  8, 3, 1, 1, true>(smem, tid, t1, aB, bB, aoff, boff, bfr, acc);
    do_phase<0, 1, 0, -1, 0, 0, 0, true>(smem, tid, t2, aB, bB, aoff, boff, bfr, acc);
    do_phase<0, 1, 1,  8, 0, 1, 0, true>(smem, tid, t2, aB, bB, aoff, boff, bfr, acc);
    do_phase<1, 0, 0, -1, 1, 0, 1, true>(smem, tid, t2, aB, bB, aoff, boff, bfr, acc);
    do_phase<1, 0, 1,  8, 1, 1, 1, true>(smem, tid, t2, aB, bB, aoff, boff, bfr, acc);
    do_phase<1, 1, 0, -1, 2, 0, 0, true>(smem, tid, t3, aB, bB, aoff, boff, bfr, acc);
    do_phase<1, 1, 1,  8, 2, 1, 0, true>(smem, tid, t3, aB, bB, aoff, boff, bfr, acc);
  }
  // epilogue iter (tiles ntk-2, ntk-1): only (ntk-1) k1 left to stage; drain
  do_phase<0, 0, 0, -1, 3, 0, 1, true >(smem, tid, ntk - 1, aB, bB, aoff, boff, bfr, acc);
  do_phase<0, 0, 1,  8, 3, 1, 1, true >(smem, tid, ntk - 1, aB, bB, aoff, boff, bfr, acc);
  do_phase<0, 1, 0, -1, 0, 0, 0, false>(smem, tid, 0, aB, bB, aoff, boff, bfr, acc);
  do_phase<0, 1, 1,  4, 0, 0, 0, false>(smem, tid, 0, aB, bB, aoff, boff, bfr, acc);
  do_phase<1, 0, 0, -1, 0, 0, 0, false>(smem, tid, 0, aB, bB, aoff, boff, bfr, acc);
  do_phase<1, 0, 1,  0, 0, 0, 0, false>(smem, tid, 0, aB, bB, aoff, boff, bfr, acc);
  do_phase<1, 1, 0, -1, 0, 0, 0, false>(smem, tid, 0, aB, bB, aoff, boff, bfr, acc);
  do_phase<1, 1, 1, -1, 0, 0, 0, false>(smem, tid, 0, aB, bB, aoff, boff, bfr, acc);

  // store: C/D map col=lane&15, row=(lane>>4)*4+reg
#pragma unroll
  for (int m = 0; m < 8; ++m) {
#pragma unroll
    for (int t = 0; t < 4; ++t) {
      const int rt = wr * 128 + m * 16 + kg * 4 + t;
      const int pr = perm[pbase + rt];
      if (pr < 0) continue;
      float* orow = out + (size_t)pr * DIM + nbase + wc * 64;
#pragma unroll
      for (int n = 0; n < 4; ++n) {
        if (tailk) atomicAdd(&orow[n * 16 + fr], acc[m][n][t]);
        else       __builtin_nontemporal_store(acc[m][n][t], &orow[n * 16 + fr]);
      }
    }
  }
}

// ---------------------------------------------------------------------------
// Kernel 4b: fallback 2-phase 128x128 grouped GEMM (R2-proven), low-ws tiers.
// ---------------------------------------------------------------------------
template <bool USE_XB>
__global__ __launch_bounds__(256) void gemm_kernel(
    const unsigned short* __restrict__ xb, const float* __restrict__ xf,
    const unsigned short* __restrict__ Wt,
    const int* __restrict__ perm, const int* __restrict__ meta,
    float* __restrict__ out, int j0, int npp) {
  const int ntiles = meta[17];
  const int mt = blockIdx.x;
  if (mt >= ntiles) return;
  const int adapter = meta[32 + 3 * mt];
  if (adapter < j0 || adapter >= j0 + npp) return;
  const int slot = adapter - j0;
  const int nt = blockIdx.y;
  const int pbase = meta[32 + 3 * mt + 1];
  const int nbase = nt << 7;

  __shared__ __align__(16) unsigned short As[BM1 * 64];
  __shared__ __align__(16) unsigned short Bs[BM1 * 64];

  const int tid = threadIdx.x;
  const int lane = tid & 63;
  const int wave = tid >> 6;

  const unsigned short* aSrcB[4];
  const float* aSrcF[4];
  const unsigned short* bSrc[4];
  unsigned short* aDst[4];
  unsigned short* bDst[4];
#pragma unroll
  for (int q = 0; q < 4; ++q) {
    const int c = wave * 4 + q;
    const int r = c * 8 + (lane >> 3);
    int pr = perm[pbase + r];
    if (pr < 0) pr = 0;
    if (USE_XB) aSrcB[q] = xb + (size_t)pr * DIM + (lane & 7) * 8;
    else        aSrcF[q] = xf + (size_t)pr * DIM + (lane & 7) * 8;
    bSrc[q] = Wt + ((size_t)slot * DIM + nbase + r) * DIM + (lane & 7) * 8;
    aDst[q] = As + c * 512;
    bDst[q] = Bs + c * 512;
  }

  const int wr = wave >> 1, wc = wave & 1;
  const int fr = lane & 15, kg = lane >> 4;

  const f32x4 zero = {0.f, 0.f, 0.f, 0.f};
  f32x4 acc[4][4];
#pragma unroll
  for (int m = 0; m < 4; ++m)
#pragma unroll
    for (int n = 0; n < 4; ++n) acc[m][n] = zero;

  for (int k0 = 0; k0 < DIM; k0 += 64) {
    if (USE_XB) {
#pragma unroll
      for (int q = 0; q < 4; ++q) gload_lds16(aSrcB[q] + k0, aDst[q]);
    } else {
#pragma unroll
      for (int q = 0; q < 4; ++q) {
        const float4 va = *(const float4*)(aSrcF[q] + k0);
        const float4 vb = *(const float4*)(aSrcF[q] + k0 + 4);
        union { bf16x8 v; unsigned short s[8]; } u;
        u.s[0] = f2bf(va.x); u.s[1] = f2bf(va.y); u.s[2] = f2bf(va.z); u.s[3] = f2bf(va.w);
        u.s[4] = f2bf(vb.x); u.s[5] = f2bf(vb.y); u.s[6] = f2bf(vb.z); u.s[7] = f2bf(vb.w);
        *(bf16x8*)(aDst[q] + lane * 8) = u.v;
      }
    }
#pragma unroll
    for (int q = 0; q < 4; ++q) gload_lds16(bSrc[q] + k0, bDst[q]);
    __syncthreads();
#pragma unroll
    for (int kk = 0; kk < 2; ++kk) {
      bf16x8 a[4], b[4];
#pragma unroll
      for (int m = 0; m < 4; ++m)
        a[m] = *(const bf16x8*)(&As[(wr * 64 + m * 16 + fr) * 64 + kk * 32 + kg * 8]);
#pragma unroll
      for (int n = 0; n < 4; ++n)
        b[n] = *(const bf16x8*)(&Bs[(wc * 64 + n * 16 + fr) * 64 + kk * 32 + kg * 8]);
#pragma unroll
      for (int m = 0; m < 4; ++m)
#pragma unroll
        for (int n = 0; n < 4; ++n)
          acc[m][n] = __builtin_amdgcn_mfma_f32_16x16x32_bf16(a[m], b[n], acc[m][n], 0, 0, 0);
    }
    __syncthreads();
  }

#pragma unroll
  for (int m = 0; m < 4; ++m) {
#pragma unroll
    for (int t = 0; t < 4; ++t) {
      const int rt = wr * 64 + m * 16 + kg * 4 + t;
      const int pr = perm[pbase + rt];
      if (pr < 0) continue;
      float* orow = out + (size_t)pr * DIM + nbase + wc * 64;
#pragma unroll
      for (int n = 0; n < 4; ++n) orow[n * 16 + fr] = acc[m][n][t];
    }
  }
}

// ---------------------------------------------------------------------------
extern "C" void kernel_launch(void* const* d_in, const int* in_sizes, int n_in,
                              void* d_out, int out_size, void* d_ws, size_t ws_size,
                              hipStream_t stream) {
  const float* x  = (const float*)d_in[0];
  const int* widx = (const int*)d_in[1];
  const float* Wb = (const float*)d_in[2];
  const float* Am = (const float*)d_in[3];
  const float* Bm = (const float*)d_in[4];
  const float* DW = (const float*)d_in[5];
  float* out = (float*)d_out;

  const size_t XB_BYTES = (size_t)T_TOKENS * DIM * 2;
  const size_t WT1_BYTES = (size_t)DIM * DIM * 2;
  const size_t PM_BYTES = 16384 * sizeof(int) + 4096;

  int npp = 0;
  bool use_xb = true;
  for (int cand = NADAPT; cand >= 1; cand >>= 1) {
    if (XB_BYTES + (size_t)cand * WT1_BYTES + PM_BYTES <= ws_size) { npp = cand; break; }
  }
  if (npp == 0) { npp = 1; use_xb = false; }

  bool use8 = (npp == NADAPT) &&
      (hipFuncSetAttribute((const void*)gemm8_all_kernel,
                           hipFuncAttributeMaxDynamicSharedMemorySize, 131072) == hipSuccess);

  char* ws = (char*)d_ws;
  unsigned short* xb = (unsigned short*)ws;
  unsigned short* Wt = (unsigned short*)(ws + (use_xb ? XB_BYTES : 0));
  char* tail = (char*)Wt + (size_t)npp * WT1_BYTES;
  int* perm = (int*)tail;
  int* meta = (int*)(tail + 16384 * sizeof(int));

  prep_kernel<<<dim3(1), dim3(1024), 0, stream>>>(widx, perm, meta, use8 ? BM2 : BM1);

  if (npp == NADAPT && use8) {
    // fused: build W_tot + convert x->bf16 + zero tail rows, one dispatch
    fused_build_kernel<<<dim3(FUSED_GRID), dim3(256), 0, stream>>>(
        Wb, Am, Bm, DW, Wt, x, xb, perm, meta, out);
    gemm8_all_kernel<<<dim3(GRIDXALL), dim3(512), 131072, stream>>>(
        xb, Wt, perm, meta, out);
  } else if (npp == NADAPT) {
    convert_zero_kernel<<<dim3(16384), dim3(256), 0, stream>>>(
        x, xb, perm, meta, out, 0);
    fused_build_kernel<<<dim3(BUILD_BLK), dim3(256), 0, stream>>>(
        Wb, Am, Bm, DW, Wt, x, xb, perm, meta, out);
    gemm_kernel<true><<<dim3(MAXT1, DIM / 128), dim3(256), 0, stream>>>(
        xb, nullptr, Wt, perm, meta, out, 0, NADAPT);
  } else {
    if (use_xb)
      convert_zero_kernel<<<dim3(16384), dim3(256), 0, stream>>>(
          x, xb, perm, meta, out, 0);
    const int passes = NADAPT / npp;
    for (int p = 0; p < passes; ++p) {
      const int j0 = p * npp;
      build_wtot_kernel<<<dim3(DIM / 64, DIM / 64, npp), dim3(256), 0, stream>>>(
          Wb, Am, Bm, DW, Wt, j0);
      if (use_xb)
        gemm_kernel<true><<<dim3(MAXT1, DIM / 128), dim3(256), 0, stream>>>(
            xb, nullptr, Wt, perm, meta, out, j0, npp);
      else
        gemm_kernel<false><<<dim3(MAXT1, DIM / 128), dim3(256), 0, stream>>>(
            nullptr, x, Wt, perm, meta, out, j0, npp);
    }
  }
}

// Round 15
// 590.423 us; speedup vs baseline: 1.0123x; 1.0123x over previous
//
#include <hip/hip_runtime.h>

// ---------------------------------------------------------------------------
// out = x @ W_base^T + x[t] @ (DeltaW[j] + A[j]B[j]);  T=8192, D=4096, J=8, R=16.
// W_tot[j][o][i] = Wb[o][i] + DW[j][i][o] + (A@B)[i][o]  (bf16, [N][K]), then
// ONE grouped GEMM (merged pass1 + split-K tail, R13-proven, 383us).
// R15: revert R14's fusion (contended, -7us). Build: Dl tile stored bf16 ->
//      LDS 49->33KB (3->4 blocks/CU) + half Dl LDS traffic; numerically safe
//      (W_tot is bf16-rounded anyway; extra error ~1 ulp of DW).
// ---------------------------------------------------------------------------

#define T_TOKENS 8192
#define DIM 4096
#define NADAPT 8
#define RANK 16

#define BM2 256
#define GRIDX1 512            // pass-1 domain: mt<32, 32x16, %8==0
#define GRIDXALL 1024         // + 512 tail split-K blocks

#define BM1 128
#define MAXT1 72

typedef __attribute__((ext_vector_type(8))) short bf16x8;
typedef __attribute__((ext_vector_type(4))) float f32x4;

__device__ __forceinline__ unsigned short f2bf(float f) {
  union { float f; unsigned u; } v; v.f = f;
  unsigned r = v.u + 0x7FFFu + ((v.u >> 16) & 1u);   // RNE
  return (unsigned short)(r >> 16);
}

__device__ __forceinline__ float bf2f(unsigned short u) {
  union { unsigned u; float f; } v; v.u = ((unsigned)u) << 16;
  return v.f;
}

__device__ __forceinline__ void gload_lds16(const void* g, void* l) {
  __builtin_amdgcn_global_load_lds(
      (const __attribute__((address_space(1))) void*)g,
      (__attribute__((address_space(3))) void*)l, 16, 0, 0);
}

template <int N> __device__ __forceinline__ void vmwait() {
  if constexpr (N == 0)      asm volatile("s_waitcnt vmcnt(0)" ::: "memory");
  else if constexpr (N == 4) asm volatile("s_waitcnt vmcnt(4)" ::: "memory");
  else if constexpr (N == 8) asm volatile("s_waitcnt vmcnt(8)" ::: "memory");
  // N < 0: no wait
}

// ---------------------------------------------------------------------------
// Kernel 1: group tokens by adapter (stable compaction), tile descriptors.
// ---------------------------------------------------------------------------
__global__ void prep_kernel(const int* __restrict__ idx, int* __restrict__ perm,
                            int* __restrict__ meta, int padm) {
  __shared__ int s_cnt[NADAPT];
  __shared__ int s_padoff[NADAPT + 1];
  __shared__ int s_wsum[16];
  const int tid = threadIdx.x;
  const int lane = tid & 63;
  const int wave = tid >> 6;

  if (tid < NADAPT) s_cnt[tid] = 0;
  __syncthreads();
  for (int t = tid; t < T_TOKENS; t += 1024) atomicAdd(&s_cnt[idx[t]], 1);
  __syncthreads();

  if (tid == 0) {
    int off = 0, nt = 0;
    for (int j = 0; j < NADAPT; ++j) {
      meta[j] = s_cnt[j];
      s_padoff[j] = off;
      const int c = s_cnt[j];
      const int ntj = (c + padm - 1) / padm;
      for (int i = 0; i < ntj; ++i) {
        meta[32 + 3 * nt + 0] = j;
        meta[32 + 3 * nt + 1] = off + i * padm;
        meta[32 + 3 * nt + 2] = min(padm, c - i * padm);
        ++nt;
      }
      off += ntj * padm;
    }
    s_padoff[NADAPT] = off;
    meta[17] = nt;
    for (int j = 0; j <= NADAPT; ++j) meta[8 + j] = s_padoff[j];
  }
  __syncthreads();

  const int total_pad = s_padoff[NADAPT];
  for (int t = tid; t < total_pad; t += 1024) perm[t] = -1;
  __syncthreads();

  for (int j = 0; j < NADAPT; ++j) {
    int base = s_padoff[j];
    for (int c0 = 0; c0 < T_TOKENS; c0 += 1024) {
      const int t = c0 + tid;
      const int flag = (idx[t] == j) ? 1 : 0;
      const unsigned long long bal = __ballot(flag);
      const int wpos = __popcll(bal & ((1ULL << lane) - 1ULL));
      if (lane == 0) s_wsum[wave] = __popcll(bal);
      __syncthreads();
      int woff = 0, ctot = 0;
      for (int w = 0; w < 16; ++w) {
        const int v = s_wsum[w];
        if (w < wave) woff += v;
        ctot += v;
      }
      if (flag) perm[base + woff + wpos] = t;
      base += ctot;
      __syncthreads();
    }
  }
}

// ---------------------------------------------------------------------------
// Kernel 2: x fp32 -> bf16 (NT loads) + zero tail out-rows (blocks >= 16384).
// ---------------------------------------------------------------------------
__global__ void convert_zero_kernel(const float* __restrict__ x,
                                    unsigned short* __restrict__ xb,
                                    const int* __restrict__ perm,
                                    const int* __restrict__ meta,
                                    float* __restrict__ out, int do_zero) {
  const int tid = threadIdx.x;
  if (blockIdx.x < 16384) {
    const long long i = (long long)blockIdx.x * 256 + tid;
    const f32x4* x4 = (const f32x4*)x;
    const f32x4 a = __builtin_nontemporal_load(&x4[2 * i]);
    const f32x4 b = __builtin_nontemporal_load(&x4[2 * i + 1]);
    uint4 o;
    o.x = (unsigned)f2bf(a.x) | ((unsigned)f2bf(a.y) << 16);
    o.y = (unsigned)f2bf(a.z) | ((unsigned)f2bf(a.w) << 16);
    o.z = (unsigned)f2bf(b.x) | ((unsigned)f2bf(b.y) << 16);
    o.w = (unsigned)f2bf(b.z) | ((unsigned)f2bf(b.w) << 16);
    ((uint4*)xb)[i] = o;
  } else if (do_zero) {
    const int b = blockIdx.x - 16384;     // 0..511
    const int mth = b >> 5;
    const int strip = b & 31;
    const int ntiles = meta[17];
    const int mt = 32 + (mth >> 1);
    if (mt >= ntiles) return;
    const int pbase = meta[32 + 3 * mt + 1] + (mth & 1) * 128;
    const int row = tid >> 1;
    const int c0 = strip * 128 + (tid & 1) * 64;
    const int pr = perm[pbase + row];
    if (pr < 0) return;
    float4* p = (float4*)(out + (size_t)pr * DIM + c0);
    const float4 z = {0.f, 0.f, 0.f, 0.f};
#pragma unroll
    for (int k = 0; k < 16; ++k) p[k] = z;
  }
}

// ---------------------------------------------------------------------------
// Kernel 3a (npp==8): j-looped W_tot build, double-buffered reg prefetch
// (R9-proven). R15: Dl stored bf16 -> 33KB LDS, 4 blocks/CU.
// ---------------------------------------------------------------------------
__global__ __launch_bounds__(256) void build_wtot_all_kernel(
    const float* __restrict__ Wb, const float* __restrict__ Am,
    const float* __restrict__ Bm, const float* __restrict__ DW,
    unsigned short* __restrict__ Wt) {
  const int i0 = blockIdx.x << 6;
  const int o0 = blockIdx.y << 6;
  __shared__ unsigned short Dl[2][64 * 64];   // bf16, quad-XOR swizzled
  __shared__ float Alt[2][16][68];
  __shared__ float Bl[2][16][68];
  const int tid = threadIdx.x;
  const int to = (tid >> 4) << 2;
  const int ti = (tid & 15) << 2;

  f32x4 wbr[4];
#pragma unroll
  for (int m = 0; m < 4; ++m)
    wbr[m] = __builtin_nontemporal_load(
        (const f32x4*)(Wb + (size_t)(o0 + to + m) * DIM + i0 + ti));

  const int di = tid >> 4;
  const int do4 = (tid & 15) << 2;
  const int ar_i = tid >> 2, ar_r4 = (tid & 3) << 2;
  const int br_r = tid >> 4, br_o4 = (tid & 15) << 2;

  f32x4 dwr[4];
  float4 ar, brv;
  {
    const float* dwp = DW + (size_t)i0 * DIM + o0;
#pragma unroll
    for (int q = 0; q < 4; ++q)
      dwr[q] = __builtin_nontemporal_load(
          (const f32x4*)(dwp + (size_t)(q * 16 + di) * DIM + do4));
    ar = *(const float4*)(Am + ((size_t)(i0 + ar_i)) * RANK + ar_r4);
    brv = *(const float4*)(Bm + (size_t)br_r * DIM + o0 + br_o4);
  }
#pragma unroll
  for (int q = 0; q < 4; ++q) {
    const int i = q * 16 + di;
    const int iq = i >> 2, ie = i & 3;
#pragma unroll
    for (int k = 0; k < 4; ++k) {
      const int o = do4 + k;
      Dl[0][o * 64 + (((iq ^ (o & 15)) << 2) | ie)] = f2bf(dwr[q][k]);
    }
  }
#pragma unroll
  for (int k = 0; k < 4; ++k) Alt[0][ar_r4 + k][ar_i] = ((const float*)&ar)[k];
  *(float4*)&Bl[0][br_r][br_o4] = brv;
  __syncthreads();

  for (int j = 0; j < NADAPT; ++j) {
    const int pb = j & 1;
    if (j + 1 < NADAPT) {
      const float* dwp = DW + ((size_t)(j + 1) * DIM + i0) * DIM + o0;
#pragma unroll
      for (int q = 0; q < 4; ++q)
        dwr[q] = __builtin_nontemporal_load(
            (const f32x4*)(dwp + (size_t)(q * 16 + di) * DIM + do4));
      ar = *(const float4*)(Am + ((size_t)(j + 1) * DIM + i0 + ar_i) * RANK + ar_r4);
      brv = *(const float4*)(Bm + ((size_t)(j + 1) * RANK + br_r) * DIM + o0 + br_o4);
    }
    float acc[4][4];
#pragma unroll
    for (int m = 0; m < 4; ++m) {
      const int o = to + m;
      const ushort4 d = *(const ushort4*)&Dl[pb][o * 64 + (((ti >> 2) ^ (o & 15)) << 2)];
      acc[m][0] = wbr[m].x + bf2f(d.x); acc[m][1] = wbr[m].y + bf2f(d.y);
      acc[m][2] = wbr[m].z + bf2f(d.z); acc[m][3] = wbr[m].w + bf2f(d.w);
    }
#pragma unroll
    for (int r = 0; r < RANK; ++r) {
      const float4 av = *(const float4*)&Alt[pb][r][ti];
      const float4 bv = *(const float4*)&Bl[pb][r][to];
#pragma unroll
      for (int m = 0; m < 4; ++m) {
        const float b = ((const float*)&bv)[m];
        acc[m][0] += b * av.x; acc[m][1] += b * av.y;
        acc[m][2] += b * av.z; acc[m][3] += b * av.w;
      }
    }
#pragma unroll
    for (int m = 0; m < 4; ++m) {
      const int o = to + m;
      const unsigned lo = (unsigned)f2bf(acc[m][0]) | ((unsigned)f2bf(acc[m][1]) << 16);
      const unsigned hi = (unsigned)f2bf(acc[m][2]) | ((unsigned)f2bf(acc[m][3]) << 16);
      uint2 pk; pk.x = lo; pk.y = hi;
      *(uint2*)(Wt + ((size_t)j * DIM + o0 + o) * DIM + i0 + ti) = pk;
    }
    if (j + 1 < NADAPT) {
      const int nb = pb ^ 1;
#pragma unroll
      for (int q = 0; q < 4; ++q) {
        const int i = q * 16 + di;
        const int iq = i >> 2, ie = i & 3;
#pragma unroll
        for (int k = 0; k < 4; ++k) {
          const int o = do4 + k;
          Dl[nb][o * 64 + (((iq ^ (o & 15)) << 2) | ie)] = f2bf(dwr[q][k]);
        }
      }
#pragma unroll
      for (int k = 0; k < 4; ++k) Alt[nb][ar_r4 + k][ar_i] = ((const float*)&ar)[k];
      *(float4*)&Bl[nb][br_r][br_o4] = brv;
      __syncthreads();
    }
  }
}

// ---------------------------------------------------------------------------
// Kernel 3b (npp<8 fallback tiers): per-adapter W_tot build (R4-proven).
// ---------------------------------------------------------------------------
__global__ __launch_bounds__(256) void build_wtot_kernel(
    const float* __restrict__ Wb, const float* __restrict__ Am,
    const float* __restrict__ Bm, const float* __restrict__ DW,
    unsigned short* __restrict__ Wt, int j0) {
  const int jj = blockIdx.z;
  const int j = j0 + jj;
  const int i0 = blockIdx.x << 6;
  const int o0 = blockIdx.y << 6;
  __shared__ float Dl[64 * 64];
  __shared__ float Alt[16][68];
  __shared__ float Bl[16][68];
  const int tid = threadIdx.x;

  const float* dwp = DW + ((size_t)j * DIM + i0) * DIM + o0;
#pragma unroll
  for (int q = 0; q < 4; ++q) {
    const int lin = q * 256 + tid;
    const int i = lin >> 4;
    const int o4 = (lin & 15) << 2;
    const float4 v = *(const float4*)(dwp + (size_t)i * DIM + o4);
    const int iq = i >> 2, ie = i & 3;
#pragma unroll
    for (int k = 0; k < 4; ++k) {
      const int o = o4 + k;
      Dl[o * 64 + (((iq ^ (o & 15)) << 2) | ie)] = ((const float*)&v)[k];
    }
  }
  {
    const int ai = tid >> 2, r4 = (tid & 3) << 2;
    const float4 v = *(const float4*)(Am + ((size_t)j * DIM + i0 + ai) * RANK + r4);
#pragma unroll
    for (int k = 0; k < 4; ++k) Alt[r4 + k][ai] = ((const float*)&v)[k];
  }
  {
    const int br = tid >> 4, bo4 = (tid & 15) << 2;
    const float4 v = *(const float4*)(Bm + ((size_t)j * RANK + br) * DIM + o0 + bo4);
    *(float4*)&Bl[br][bo4] = v;
  }
  __syncthreads();

  const int to = (tid >> 4) << 2;
  const int ti = (tid & 15) << 2;
  float acc[4][4];

#pragma unroll
  for (int m = 0; m < 4; ++m) {
    const int o = to + m;
    const float4 w = *(const float4*)(Wb + (size_t)(o0 + o) * DIM + i0 + ti);
    const float4 d = *(const float4*)&Dl[o * 64 + (((ti >> 2) ^ (o & 15)) << 2)];
    acc[m][0] = w.x + d.x; acc[m][1] = w.y + d.y;
    acc[m][2] = w.z + d.z; acc[m][3] = w.w + d.w;
  }
#pragma unroll
  for (int r = 0; r < RANK; ++r) {
    const float4 av = *(const float4*)&Alt[r][ti];
    const float4 bv = *(const float4*)&Bl[r][to];
#pragma unroll
    for (int m = 0; m < 4; ++m) {
      const float b = ((const float*)&bv)[m];
      acc[m][0] += b * av.x; acc[m][1] += b * av.y;
      acc[m][2] += b * av.z; acc[m][3] += b * av.w;
    }
  }
#pragma unroll
  for (int m = 0; m < 4; ++m) {
    const int o = to + m;
    const unsigned lo = (unsigned)f2bf(acc[m][0]) | ((unsigned)f2bf(acc[m][1]) << 16);
    const unsigned hi = (unsigned)f2bf(acc[m][2]) | ((unsigned)f2bf(acc[m][3]) << 16);
    uint2 pk; pk.x = lo; pk.y = hi;
    *(uint2*)(Wt + ((size_t)jj * DIM + o0 + o) * DIM + i0 + ti) = pk;
  }
}

// ---------------------------------------------------------------------------
// Kernel 4a: merged 8-phase 256x256 grouped GEMM (R13-proven).
// blocks <512: mt<32, full K (ntk=64), NT-store epilogue, XCD-swizzled.
// blocks >=512: tail mt>=32, split-K x4 (ntk=16, kc=0..3), atomicAdd epilogue.
// ---------------------------------------------------------------------------
template <int BUF, int KK, int MQ, int VME, int SGRP, int SOP, int SKH, bool DOST>
__device__ __forceinline__ void do_phase(
    char* smem, int tid, int stile,
    const unsigned short* const* aB, const unsigned short* const* bB,
    const int* aoff, const int* boff, bf16x8* bfr, f32x4 (*acc)[4]) {
  const int grp = (BUF * 2 + KK) * 16384;
  if constexpr (MQ == 0) {
#pragma unroll
    for (int n = 0; n < 4; ++n)
      bfr[n] = *(const bf16x8*)(smem + 65536 + grp + boff[n]);
  }
  bf16x8 afr[4];
#pragma unroll
  for (int i = 0; i < 4; ++i)
    afr[i] = *(const bf16x8*)(smem + grp + aoff[MQ * 4 + i]);
  if constexpr (DOST) {
    const unsigned short* const* bs = SOP ? bB : aB;
#pragma unroll
    for (int q = 0; q < 2; ++q)
      gload_lds16(bs[q] + stile * 64 + SKH * 32,
                  smem + SOP * 65536 + SGRP * 16384 + q * 8192 + tid * 16);
  }
  __builtin_amdgcn_s_barrier();
  asm volatile("s_waitcnt lgkmcnt(0)" ::: "memory");
  __builtin_amdgcn_s_setprio(1);
#pragma unroll
  for (int i = 0; i < 4; ++i)
#pragma unroll
    for (int n = 0; n < 4; ++n)
      acc[MQ * 4 + i][n] =
          __builtin_amdgcn_mfma_f32_16x16x32_bf16(afr[i], bfr[n], acc[MQ * 4 + i][n], 0, 0, 0);
  __builtin_amdgcn_s_setprio(0);
  vmwait<VME>();
  __builtin_amdgcn_s_barrier();
}

template <int SGRP, int SOP, int SKH>
__device__ __forceinline__ void do_stage(
    char* smem, int tid, int stile,
    const unsigned short* const* aB, const unsigned short* const* bB) {
  const unsigned short* const* bs = SOP ? bB : aB;
#pragma unroll
  for (int q = 0; q < 2; ++q)
    gload_lds16(bs[q] + stile * 64 + SKH * 32,
                smem + SOP * 65536 + SGRP * 16384 + q * 8192 + tid * 16);
}

__global__ __launch_bounds__(512, 2) void gemm8_all_kernel(
    const unsigned short* __restrict__ xb, const unsigned short* __restrict__ Wt,
    const int* __restrict__ perm, const int* __restrict__ meta,
    float* __restrict__ out) {
  extern __shared__ char smem[];
  const int ntiles = meta[17];
  const int flat = blockIdx.x;
  int mt, nt, kc, ntk;
  bool tailk;
  if (flat < GRIDX1) {
    const int swz = (flat & 7) * (GRIDX1 / 8) + (flat >> 3);   // XCD-chunked
    mt = swz >> 4; nt = swz & 15; kc = 0; ntk = 64; tailk = false;
  } else {
    const int f = flat - GRIDX1;
    kc = f >> 7;                    // 0..3 K-chunks
    const int r = f & 127;
    mt = 32 + (r >> 4); nt = r & 15; ntk = 16; tailk = true;
  }
  if (mt >= ntiles) return;
  const int adapter = meta[32 + 3 * mt];
  const int pbase = meta[32 + 3 * mt + 1];
  const int nbase = nt << 8;
  const size_t kbase = (size_t)kc * ((size_t)ntk * 64);

  const int tid = threadIdx.x;
  const int lane = tid & 63;
  const int wave = tid >> 6;
  const int wr = wave >> 2, wc = wave & 3;       // 2M x 4N waves
  const int fr = lane & 15, kg = lane >> 4;

  int aoff[8], boff[4];
#pragma unroll
  for (int m = 0; m < 8; ++m) {
    const int row = wr * 128 + m * 16 + fr;
    const int r = row >> 1, hf = row & 1;
    const int c = ((hf << 2) | kg) ^ (r & 7);
    aoff[m] = r * 128 + c * 16;
  }
#pragma unroll
  for (int n = 0; n < 4; ++n) {
    const int row = wc * 64 + n * 16 + fr;
    const int r = row >> 1, hf = row & 1;
    const int c = ((hf << 2) | kg) ^ (r & 7);
    boff[n] = r * 128 + c * 16;
  }

  // stage source pointers (pre-swizzled global, linear LDS dest — rule 21)
  const unsigned short* aB[2];
  const unsigned short* bB[2];
#pragma unroll
  for (int q = 0; q < 2; ++q) {
    const int L = q * 512 + tid;
    const int r = L >> 3, c = L & 7;
    const int s = c ^ (r & 7);
    const int grow = 2 * r + (s >> 2);
    const int gk = (s & 3) << 3;
    int pr = perm[pbase + grow];
    if (pr < 0) pr = 0;
    aB[q] = xb + (size_t)pr * DIM + gk + kbase;
    bB[q] = Wt + ((size_t)adapter * DIM + nbase + grow) * DIM + gk + kbase;
  }

  const f32x4 zero = {0.f, 0.f, 0.f, 0.f};
  f32x4 acc[8][4];
#pragma unroll
  for (int m = 0; m < 8; ++m)
#pragma unroll
    for (int n = 0; n < 4; ++n) acc[m][n] = zero;
  bf16x8 bfr[4];

  // prologue: tile0 (buf0) both k-halves, tile1 (buf1) k-half0
  do_stage<0, 0, 0>(smem, tid, 0, aB, bB);
  do_stage<0, 1, 0>(smem, tid, 0, aB, bB);
  do_stage<1, 0, 1>(smem, tid, 0, aB, bB);
  do_stage<1, 1, 1>(smem, tid, 0, aB, bB);
  do_stage<2, 0, 0>(smem, tid, 1, aB, bB);
  do_stage<2, 1, 0>(smem, tid, 1, aB, bB);
  vmwait<8>();
  __builtin_amdgcn_s_barrier();

  // main loop: iter computes tiles 2it (buf0), 2it+1 (buf1)
  for (int it = 0; it < ntk / 2 - 1; ++it) {
    const int t1 = 2 * it + 1, t2 = 2 * it + 2, t3 = 2 * it + 3;
    do_phase<0, 0, 0, -1, 3, 0, 1, true>(smem, tid, t1, aB, bB, aoff, boff, bfr, acc);
    do_phase<0, 0, 1,  8, 3, 1, 1, true>(smem, tid, t1, aB, bB, aoff, boff, bfr, acc);
    do_phase<0, 1, 0, -1, 0, 0, 0, true>(smem, tid, t2, aB, bB, aoff, boff, bfr, acc);
    do_phase<0, 1, 1,  8, 0, 1, 0, true>(smem, tid, t2, aB, bB, aoff, boff, bfr, acc);
    do_phase<1, 0, 0, -1, 1, 0, 1, true>(smem, tid, t2, aB, bB, aoff, boff, bfr, acc);
    do_phase<1, 0, 1,  8, 1, 1, 1, true>(smem, tid, t2, aB, bB, aoff, boff, bfr, acc);
    do_phase<1, 1, 0, -1, 2, 0, 0, true>(smem, tid, t3, aB, bB, aoff, boff, bfr, acc);
    do_phase<1, 1, 1,  8, 2, 1, 0, true>(smem, tid, t3, aB, bB, aoff, boff, bfr, acc);
  }
  // epilogue iter (tiles ntk-2, ntk-1): only (ntk-1) k1 left to stage; drain
  do_phase<0, 0, 0, -1, 3, 0, 1, true >(smem, tid, ntk - 1, aB, bB, aoff, boff, bfr, acc);
  do_phase<0, 0, 1,  8, 3, 1, 1, true >(smem, tid, ntk - 1, aB, bB, aoff, boff, bfr, acc);
  do_phase<0, 1, 0, -1, 0, 0, 0, false>(smem, tid, 0, aB, bB, aoff, boff, bfr, acc);
  do_phase<0, 1, 1,  4, 0, 0, 0, false>(smem, tid, 0, aB, bB, aoff, boff, bfr, acc);
  do_phase<1, 0, 0, -1, 0, 0, 0, false>(smem, tid, 0, aB, bB, aoff, boff, bfr, acc);
  do_phase<1, 0, 1,  0, 0, 0, 0, false>(smem, tid, 0, aB, bB, aoff, boff, bfr, acc);
  do_phase<1, 1, 0, -1, 0, 0, 0, false>(smem, tid, 0, aB, bB, aoff, boff, bfr, acc);
  do_phase<1, 1, 1, -1, 0, 0, 0, false>(smem, tid, 0, aB, bB, aoff, boff, bfr, acc);

  // store: C/D map col=lane&15, row=(lane>>4)*4+reg
#pragma unroll
  for (int m = 0; m < 8; ++m) {
#pragma unroll
    for (int t = 0; t < 4; ++t) {
      const int rt = wr * 128 + m * 16 + kg * 4 + t;
      const int pr = perm[pbase + rt];
      if (pr < 0) continue;
      float* orow = out + (size_t)pr * DIM + nbase + wc * 64;
#pragma unroll
      for (int n = 0; n < 4; ++n) {
        if (tailk) atomicAdd(&orow[n * 16 + fr], acc[m][n][t]);
        else       __builtin_nontemporal_store(acc[m][n][t], &orow[n * 16 + fr]);
      }
    }
  }
}

// ---------------------------------------------------------------------------
// Kernel 4b: fallback 2-phase 128x128 grouped GEMM (R2-proven), low-ws tiers.
// ---------------------------------------------------------------------------
template <bool USE_XB>
__global__ __launch_bounds__(256) void gemm_kernel(
    const unsigned short* __restrict__ xb, const float* __restrict__ xf,
    const unsigned short* __restrict__ Wt,
    const int* __restrict__ perm, const int* __restrict__ meta,
    float* __restrict__ out, int j0, int npp) {
  const int ntiles = meta[17];
  const int mt = blockIdx.x;
  if (mt >= ntiles) return;
  const int adapter = meta[32 + 3 * mt];
  if (adapter < j0 || adapter >= j0 + npp) return;
  const int slot = adapter - j0;
  const int nt = blockIdx.y;
  const int pbase = meta[32 + 3 * mt + 1];
  const int nbase = nt << 7;

  __shared__ __align__(16) unsigned short As[BM1 * 64];
  __shared__ __align__(16) unsigned short Bs[BM1 * 64];

  const int tid = threadIdx.x;
  const int lane = tid & 63;
  const int wave = tid >> 6;

  const unsigned short* aSrcB[4];
  const float* aSrcF[4];
  const unsigned short* bSrc[4];
  unsigned short* aDst[4];
  unsigned short* bDst[4];
#pragma unroll
  for (int q = 0; q < 4; ++q) {
    const int c = wave * 4 + q;
    const int r = c * 8 + (lane >> 3);
    int pr = perm[pbase + r];
    if (pr < 0) pr = 0;
    if (USE_XB) aSrcB[q] = xb + (size_t)pr * DIM + (lane & 7) * 8;
    else        aSrcF[q] = xf + (size_t)pr * DIM + (lane & 7) * 8;
    bSrc[q] = Wt + ((size_t)slot * DIM + nbase + r) * DIM + (lane & 7) * 8;
    aDst[q] = As + c * 512;
    bDst[q] = Bs + c * 512;
  }

  const int wr = wave >> 1, wc = wave & 1;
  const int fr = lane & 15, kg = lane >> 4;

  const f32x4 zero = {0.f, 0.f, 0.f, 0.f};
  f32x4 acc[4][4];
#pragma unroll
  for (int m = 0; m < 4; ++m)
#pragma unroll
    for (int n = 0; n < 4; ++n) acc[m][n] = zero;

  for (int k0 = 0; k0 < DIM; k0 += 64) {
    if (USE_XB) {
#pragma unroll
      for (int q = 0; q < 4; ++q) gload_lds16(aSrcB[q] + k0, aDst[q]);
    } else {
#pragma unroll
      for (int q = 0; q < 4; ++q) {
        const float4 va = *(const float4*)(aSrcF[q] + k0);
        const float4 vb = *(const float4*)(aSrcF[q] + k0 + 4);
        union { bf16x8 v; unsigned short s[8]; } u;
        u.s[0] = f2bf(va.x); u.s[1] = f2bf(va.y); u.s[2] = f2bf(va.z); u.s[3] = f2bf(va.w);
        u.s[4] = f2bf(vb.x); u.s[5] = f2bf(vb.y); u.s[6] = f2bf(vb.z); u.s[7] = f2bf(vb.w);
        *(bf16x8*)(aDst[q] + lane * 8) = u.v;
      }
    }
#pragma unroll
    for (int q = 0; q < 4; ++q) gload_lds16(bSrc[q] + k0, bDst[q]);
    __syncthreads();
#pragma unroll
    for (int kk = 0; kk < 2; ++kk) {
      bf16x8 a[4], b[4];
#pragma unroll
      for (int m = 0; m < 4; ++m)
        a[m] = *(const bf16x8*)(&As[(wr * 64 + m * 16 + fr) * 64 + kk * 32 + kg * 8]);
#pragma unroll
      for (int n = 0; n < 4; ++n)
        b[n] = *(const bf16x8*)(&Bs[(wc * 64 + n * 16 + fr) * 64 + kk * 32 + kg * 8]);
#pragma unroll
      for (int m = 0; m < 4; ++m)
#pragma unroll
        for (int n = 0; n < 4; ++n)
          acc[m][n] = __builtin_amdgcn_mfma_f32_16x16x32_bf16(a[m], b[n], acc[m][n], 0, 0, 0);
    }
    __syncthreads();
  }

#pragma unroll
  for (int m = 0; m < 4; ++m) {
#pragma unroll
    for (int t = 0; t < 4; ++t) {
      const int rt = wr * 64 + m * 16 + kg * 4 + t;
      const int pr = perm[pbase + rt];
      if (pr < 0) continue;
      float* orow = out + (size_t)pr * DIM + nbase + wc * 64;
#pragma unroll
      for (int n = 0; n < 4; ++n) orow[n * 16 + fr] = acc[m][n][t];
    }
  }
}

// ---------------------------------------------------------------------------
extern "C" void kernel_launch(void* const* d_in, const int* in_sizes, int n_in,
                              void* d_out, int out_size, void* d_ws, size_t ws_size,
                              hipStream_t stream) {
  const float* x  = (const float*)d_in[0];
  const int* widx = (const int*)d_in[1];
  const float* Wb = (const float*)d_in[2];
  const float* Am = (const float*)d_in[3];
  const float* Bm = (const float*)d_in[4];
  const float* DW = (const float*)d_in[5];
  float* out = (float*)d_out;

  const size_t XB_BYTES = (size_t)T_TOKENS * DIM * 2;
  const size_t WT1_BYTES = (size_t)DIM * DIM * 2;
  const size_t PM_BYTES = 16384 * sizeof(int) + 4096;

  int npp = 0;
  bool use_xb = true;
  for (int cand = NADAPT; cand >= 1; cand >>= 1) {
    if (XB_BYTES + (size_t)cand * WT1_BYTES + PM_BYTES <= ws_size) { npp = cand; break; }
  }
  if (npp == 0) { npp = 1; use_xb = false; }

  bool use8 = (npp == NADAPT) &&
      (hipFuncSetAttribute((const void*)gemm8_all_kernel,
                           hipFuncAttributeMaxDynamicSharedMemorySize, 131072) == hipSuccess);

  char* ws = (char*)d_ws;
  unsigned short* xb = (unsigned short*)ws;
  unsigned short* Wt = (unsigned short*)(ws + (use_xb ? XB_BYTES : 0));
  char* tail = (char*)Wt + (size_t)npp * WT1_BYTES;
  int* perm = (int*)tail;
  int* meta = (int*)(tail + 16384 * sizeof(int));

  prep_kernel<<<dim3(1), dim3(1024), 0, stream>>>(widx, perm, meta, use8 ? BM2 : BM1);
  if (use_xb)
    convert_zero_kernel<<<dim3(16384 + 512), dim3(256), 0, stream>>>(
        x, xb, perm, meta, out, use8 ? 1 : 0);

  if (npp == NADAPT) {
    build_wtot_all_kernel<<<dim3(DIM / 64, DIM / 64), dim3(256), 0, stream>>>(
        Wb, Am, Bm, DW, Wt);
    if (use8) {
      gemm8_all_kernel<<<dim3(GRIDXALL), dim3(512), 131072, stream>>>(
          xb, Wt, perm, meta, out);
    } else {
      gemm_kernel<true><<<dim3(MAXT1, DIM / 128), dim3(256), 0, stream>>>(
          xb, nullptr, Wt, perm, meta, out, 0, NADAPT);
    }
  } else {
    const int passes = NADAPT / npp;
    for (int p = 0; p < passes; ++p) {
      const int j0 = p * npp;
      build_wtot_kernel<<<dim3(DIM / 64, DIM / 64, npp), dim3(256), 0, stream>>>(
          Wb, Am, Bm, DW, Wt, j0);
      if (use_xb)
        gemm_kernel<true><<<dim3(MAXT1, DIM / 128), dim3(256), 0, stream>>>(
            xb, nullptr, Wt, perm, meta, out, j0, npp);
      else
        gemm_kernel<false><<<dim3(MAXT1, DIM / 128), dim3(256), 0, stream>>>(
            nullptr, x, Wt, perm, meta, out, j0, npp);
    }
  }
}